// Round 7
// baseline (122.343 us; speedup 1.0000x reference)
//
#include <hip/hip_runtime.h>

typedef unsigned short u16;
typedef __attribute__((ext_vector_type(8))) short bf16x8;
typedef __attribute__((ext_vector_type(4))) float f32x4;
typedef __attribute__((ext_vector_type(8))) unsigned short u16x8;
typedef __attribute__((ext_vector_type(4))) unsigned short u16x4;
typedef __attribute__((ext_vector_type(2))) unsigned short u16x2;

// ---- bf16 helpers (RNE) ----
__device__ __forceinline__ u16 f2b(float f) {
  unsigned u = __builtin_bit_cast(unsigned, f);
  unsigned r = (u + 0x7fffu + ((u >> 16) & 1u)) >> 16;
  return (u16)r;
}
__device__ __forceinline__ float b2f(u16 u) {
  return __builtin_bit_cast(float, ((unsigned)u) << 16);
}
__device__ __forceinline__ void gload16(const void* g, void* l) {
  __builtin_amdgcn_global_load_lds(
      (const __attribute__((address_space(1))) unsigned int*)g,
      (__attribute__((address_space(3))) unsigned int*)l, 16, 0, 0);
}

// ---- fused prep: x cast (2048) | waT (1536) | wpT (1024) | rope tab (256) ----
__global__ __launch_bounds__(256) void k_prep(const float* __restrict__ x,
                                              const float* __restrict__ wa,
                                              const float* __restrict__ wp,
                                              u16* __restrict__ xb,
                                              u16* __restrict__ waT,
                                              u16* __restrict__ wpT,
                                              float2* __restrict__ tab) {
  __shared__ float t[32][33];
  const int idx = blockIdx.x;
  const int tid = threadIdx.x;
  if (idx < 2048) {                       // cast x -> bf16, 8 elems/thread
    int i = idx * 256 + tid;
    float4 v0 = ((const float4*)x)[i * 2];
    float4 v1 = ((const float4*)x)[i * 2 + 1];
    u16x8 o;
    o[0] = f2b(v0.x); o[1] = f2b(v0.y); o[2] = f2b(v0.z); o[3] = f2b(v0.w);
    o[4] = f2b(v1.x); o[5] = f2b(v1.y); o[6] = f2b(v1.z); o[7] = f2b(v1.w);
    ((u16x8*)xb)[i] = o;
    return;
  }
  const int tx = tid & 31, ty = tid >> 5; // transpose tiles, block as (32,8)
  if (idx < 3584) {                       // waT: (1024 x 1536) -> (1536 x 1024)
    int tt = idx - 2048;
    int c0 = (tt % 48) * 32, r0 = (tt / 48) * 32;
    for (int ii = 0; ii < 4; ++ii)
      t[ty + ii * 8][tx] = wa[(size_t)(r0 + ty + ii * 8) * 1536 + c0 + tx];
    __syncthreads();
    for (int ii = 0; ii < 4; ++ii)
      waT[(size_t)(c0 + ty + ii * 8) * 1024 + r0 + tx] = f2b(t[tx][ty + ii * 8]);
    return;
  }
  if (idx < 4608) {                       // wpT: (1024 x 1024) -> (1024 x 1024)
    int tt = idx - 3584;
    int c0 = (tt & 31) * 32, r0 = (tt >> 5) * 32;
    for (int ii = 0; ii < 4; ++ii)
      t[ty + ii * 8][tx] = wp[(size_t)(r0 + ty + ii * 8) * 1024 + c0 + tx];
    __syncthreads();
    for (int ii = 0; ii < 4; ++ii)
      wpT[(size_t)(c0 + ty + ii * 8) * 1024 + r0 + tx] = f2b(t[tx][ty + ii * 8]);
    return;
  }
  {                                       // rope table
    int e = (idx - 4608) * 256 + tid;     // 65536 entries
    int tt = e >> 5, i = e & 31;
    float inv = expf((float)(2 * i) * -0.14391156831f);
    float fr = (float)tt * inv;
    float s, c;
    sincosf(fr, &s, &c);
    tab[tt * 32 + i] = make_float2(c, s);
  }
}

// ---- GEMM: C[M,N] = A[M,K](bf16,row) * Bt[N,K](bf16,row) ----
// 64x128 tile, BK=64, 4 waves 2x2, XOR-swizzled LDS (rule 21).
template<int OUT_BF16>
__global__ __launch_bounds__(256) void k_gemm_bt(const u16* __restrict__ A,
                                                 const u16* __restrict__ Bt,
                                                 void* __restrict__ Cv,
                                                 int M, int N, int K) {
  __shared__ u16 lA[64 * 64];
  __shared__ u16 lB[128 * 64];
  const int tid = threadIdx.x;
  const int lane = tid & 63, w = tid >> 6;
  const int wr = w >> 1, wc = w & 1;
  const int la = lane & 15, hi = lane >> 4;
  const int bm0 = blockIdx.y * 64, bn0 = blockIdx.x * 128;
  const f32x4 zero = {0.f, 0.f, 0.f, 0.f};
  f32x4 acc[2][4];
#pragma unroll
  for (int m = 0; m < 2; ++m)
#pragma unroll
    for (int n = 0; n < 4; ++n) acc[m][n] = zero;

  const int r = tid >> 3;           // staging row within round (0..31)
  const int s = tid & 7;            // staging slot
  for (int k0 = 0; k0 < K; k0 += 64) {
#pragma unroll
    for (int rr = 0; rr < 2; ++rr) {
      int row = rr * 32 + r;
      gload16(A + (size_t)(bm0 + row) * K + k0 + ((s ^ (row & 7)) << 3),
              &lA[(rr * 256 + tid) * 8]);
    }
#pragma unroll
    for (int rr = 0; rr < 4; ++rr) {
      int row = rr * 32 + r;
      gload16(Bt + (size_t)(bn0 + row) * K + k0 + ((s ^ (row & 7)) << 3),
              &lB[(rr * 256 + tid) * 8]);
    }
    __syncthreads();
#pragma unroll
    for (int kk = 0; kk < 2; ++kk) {
      bf16x8 af[2], bfr[4];
#pragma unroll
      for (int m = 0; m < 2; ++m) {
        int R = wr * 32 + m * 16 + la;
        af[m] = *(const bf16x8*)&lA[R * 64 + (((kk * 4 + hi) ^ (R & 7)) << 3)];
      }
#pragma unroll
      for (int n = 0; n < 4; ++n) {
        int R = wc * 64 + n * 16 + la;
        bfr[n] = *(const bf16x8*)&lB[R * 64 + (((kk * 4 + hi) ^ (R & 7)) << 3)];
      }
#pragma unroll
      for (int m = 0; m < 2; ++m)
#pragma unroll
        for (int n = 0; n < 4; ++n)
          acc[m][n] = __builtin_amdgcn_mfma_f32_16x16x32_bf16(af[m], bfr[n], acc[m][n], 0, 0, 0);
    }
    __syncthreads();
  }
  float* Cf = (float*)Cv;
  u16*   Cb = (u16*)Cv;
#pragma unroll
  for (int m = 0; m < 2; ++m)
#pragma unroll
    for (int n = 0; n < 4; ++n)
#pragma unroll
      for (int j = 0; j < 4; ++j) {
        int row = bm0 + wr * 32 + m * 16 + hi * 4 + j;
        int col = bn0 + wc * 64 + n * 16 + la;
        float v = acc[m][n][j];
        if (OUT_BF16) Cb[(size_t)row * N + col] = f2b(v);
        else          Cf[(size_t)row * N + col] = v;
      }
}

// ---- fused rope_rms (2048 blocks, 2 rows each) + V transpose (1024) ----
__global__ __launch_bounds__(320) void k_rvt(const u16* __restrict__ qkv,
                                             const float2* __restrict__ tab,
                                             u16* __restrict__ Qb,
                                             u16* __restrict__ Kb,
                                             u16* __restrict__ Vt) {
  const int idx = blockIdx.x;
  const int tid = threadIdx.x;
  if (idx < 2048) {                     // rope+rms: 2 rows, 160 threads each
    const int half = (tid >= 160);
    const int lt = tid - half * 160;
    const int row = idx * 2 + half;     // b*T + t
    const int hh = lt >> 3, s = lt & 7;
    const int b = row >> 11, t = row & 2047;
    const int col = (hh < 16) ? hh * 64 : 1024 + (hh - 16) * 64;
    u16x8 xv = *(const u16x8*)(qkv + (size_t)row * 1536 + col + s * 8);
    float4 c01 = *(const float4*)(tab + t * 32 + s * 4);
    float4 c23 = *(const float4*)(tab + t * 32 + s * 4 + 2);
    float y[8];
    {
      float x0 = b2f(xv[0]), x1 = b2f(xv[1]);
      y[0] = x0 * c01.x - x1 * c01.y; y[1] = x1 * c01.x + x0 * c01.y;
      x0 = b2f(xv[2]); x1 = b2f(xv[3]);
      y[2] = x0 * c01.z - x1 * c01.w; y[3] = x1 * c01.z + x0 * c01.w;
      x0 = b2f(xv[4]); x1 = b2f(xv[5]);
      y[4] = x0 * c23.x - x1 * c23.y; y[5] = x1 * c23.x + x0 * c23.y;
      x0 = b2f(xv[6]); x1 = b2f(xv[7]);
      y[6] = x0 * c23.z - x1 * c23.w; y[7] = x1 * c23.z + x0 * c23.w;
    }
    float ss = 0.f;
#pragma unroll
    for (int e = 0; e < 8; ++e) ss += y[e] * y[e];
    ss += __shfl_xor(ss, 1, 8);
    ss += __shfl_xor(ss, 2, 8);
    ss += __shfl_xor(ss, 4, 8);
    float sc = rsqrtf(ss * (1.0f / 64.0f) + 1e-6f);
    u16x8 o;
#pragma unroll
    for (int e = 0; e < 8; ++e) o[e] = f2b(y[e] * sc);
    size_t ob;
    u16* outp;
    if (hh < 16) { outp = Qb; ob = ((size_t)((b * 16 + hh) * 2048 + t)) * 64 + s * 8; }
    else         { outp = Kb; ob = ((size_t)((b * 4 + hh - 16) * 2048 + t)) * 64 + s * 8; }
    *(u16x8*)(outp + ob) = o;
    return;
  }
  // V transpose: 1024 tile-blocks, threads 0..255 as (32,8)
  __shared__ u16 t[32][33];
  if (tid >= 256) return;
  const int ii2 = idx - 2048;
  const int bg = ii2 >> 7;              // 0..7
  const int b = bg >> 2, g = bg & 3;
  const int t0 = (ii2 & 63) * 32, d0 = ((ii2 >> 6) & 1) * 32;
  const int tx = tid & 31, ty = tid >> 5;
  const u16* src = qkv + (size_t)b * 2048 * 1536 + 1280 + g * 64;
  for (int ii = 0; ii < 4; ++ii)
    t[ty + ii * 8][tx] = src[(size_t)(t0 + ty + ii * 8) * 1536 + d0 + tx];
  __syncthreads();
  u16* dst = Vt + (size_t)bg * 64 * 2048;
  for (int ii = 0; ii < 4; ++ii)
    dst[(size_t)(d0 + ty + ii * 8) * 2048 + t0 + tx] = t[tx][ty + ii * 8];
}

// ---- causal GQA flash attention, v6 ----
// grid (32 bh, 32 qtiles), block 256 (4 waves x 16 q-rows), 4 blocks/CU.
// K: double-buffered swizzled LDS, ONE barrier/tile, prefetch ISSUED AFTER
// the barrier (regs consumed by trailing ds_write, so no vmcnt drain stall).
// V: no LDS -- per-wave register loads straight from L2-resident Vt, issued
// right after the barrier, consumed ~500cy later at PV. LDS total 24 KB.
__global__ __launch_bounds__(256, 4) void k_attn(const u16* __restrict__ Qb,
                                                 const u16* __restrict__ Kb,
                                                 const u16* __restrict__ Vtb,
                                                 u16* __restrict__ Ob) {
  __shared__ u16 lK[2][64][64];
  __shared__ u16 lP[4][16][64];
  const int bh = blockIdx.x;
  const int b = bh >> 4, h = bh & 15, g = h >> 2;
  const int y = blockIdx.y;
  // per-CU balanced qtile map: streams {a, a+8, a+16, a+24} sum to 66 iters
  const int qtile = (y < 8) ? 31 - y : (y < 16) ? y + 8 : (y < 24) ? 31 - y : y - 24;
  const int tid = threadIdx.x;
  const int lane = tid & 63, w = tid >> 6;
  const int la = lane & 15, hi = lane >> 4;
  const int qr0 = qtile * 64 + w * 16;
  const int nt = qtile + 1;

  const u16* Qg  = Qb  + (size_t)(b * 16 + h) * 2048 * 64;
  const u16* Kg  = Kb  + (size_t)(b * 4 + g) * 2048 * 64;
  const u16* Vtg = Vtb + (size_t)(b * 4 + g) * 64 * 2048;

  bf16x8 qf0, qf1;
  {
    const u16* ptr = Qg + (size_t)(qr0 + la) * 64 + hi * 8;
    qf0 = *(const bf16x8*)ptr;
    qf1 = *(const bf16x8*)(ptr + 32);
  }
  const float C = 0.18033688011f;      // 0.125 * log2(e)
  float m_ = -3e38f, l_ = 0.f;
  const f32x4 zero = {0.f, 0.f, 0.f, 0.f};
  f32x4 ao[4];
#pragma unroll
  for (int f = 0; f < 4; ++f) ao[f] = zero;

  const int sr = tid >> 3;             // staging row 0..31 (and +32)
  const int ss = (tid & 7) * 8;        // u16 col of the 16B chunk
  const int sw = ss ^ ((sr & 7) << 3); // swizzled LDS col
  const int rcc = (hi * 8) ^ ((la & 7) << 3);  // swizzled read col

  {                                    // prologue: stage K tile 0
    u16x8 k0 = *(const u16x8*)(Kg + (size_t)sr * 64 + ss);
    u16x8 k1 = *(const u16x8*)(Kg + (size_t)(sr + 32) * 64 + ss);
    *(u16x8*)(&lK[0][sr][sw])      = k0;
    *(u16x8*)(&lK[0][sr + 32][sw]) = k1;
  }

  for (int kt = 0; kt < nt; ++kt) {
    const int cur = kt & 1;
    const int kv0 = kt * 64;
    __syncthreads();                   // lK[cur] ready (written last iter)

    // issue V fragment loads for THIS tile (consumed at PV, ~500cy away)
    bf16x8 v0[4], v1[4];
#pragma unroll
    for (int f = 0; f < 4; ++f) {
      const u16* vp = Vtg + (size_t)(f * 16 + la) * 2048 + kv0 + hi * 8;
      v0[f] = *(const bf16x8*)vp;
      v1[f] = *(const bf16x8*)(vp + 32);
    }
    // issue next K tile loads (consumed by trailing ds_write)
    u16x8 kreg0, kreg1;
    if (kt + 1 < nt) {
      int kv = kv0 + 64;
      kreg0 = *(const u16x8*)(Kg + (size_t)(kv + sr) * 64 + ss);
      kreg1 = *(const u16x8*)(Kg + (size_t)(kv + sr + 32) * 64 + ss);
    }

    // S^T = K Q^T: lane -> q=la, kv = n*16 + hi*4 + j (raw z units)
    float z_[4][4];
    __builtin_amdgcn_s_setprio(1);
#pragma unroll
    for (int n = 0; n < 4; ++n) {
      const u16* kr = &lK[cur][n * 16 + la][0];
      bf16x8 kb0 = *(const bf16x8*)(kr + rcc);
      bf16x8 kb1 = *(const bf16x8*)(kr + (rcc ^ 32));
      f32x4 z = zero;
      z = __builtin_amdgcn_mfma_f32_16x16x32_bf16(kb0, qf0, z, 0, 0, 0);
      z = __builtin_amdgcn_mfma_f32_16x16x32_bf16(kb1, qf1, z, 0, 0, 0);
#pragma unroll
      for (int j = 0; j < 4; ++j) z_[n][j] = z[j];
    }
    __builtin_amdgcn_s_setprio(0);
    if (kt == nt - 1) {                // diagonal tile: causal mask
#pragma unroll
      for (int n = 0; n < 4; ++n)
#pragma unroll
        for (int j = 0; j < 4; ++j)
          if (n * 16 + hi * 4 + j > w * 16 + la) z_[n][j] = -3e38f;
    }
    // row max (max3-fusable tree) + reduce across the 4 hi-copies
    float t0 = fmaxf(fmaxf(z_[0][0], z_[0][1]), fmaxf(z_[0][2], z_[0][3]));
    float t1 = fmaxf(fmaxf(z_[1][0], z_[1][1]), fmaxf(z_[1][2], z_[1][3]));
    float t2 = fmaxf(fmaxf(z_[2][0], z_[2][1]), fmaxf(z_[2][2], z_[2][3]));
    float t3 = fmaxf(fmaxf(z_[3][0], z_[3][1]), fmaxf(z_[3][2], z_[3][3]));
    float rm = fmaxf(fmaxf(t0, t1), fmaxf(t2, t3));
    rm = fmaxf(rm, __shfl_xor(rm, 16, 64));
    rm = fmaxf(rm, __shfl_xor(rm, 32, 64));
    float al = 1.0f;
    if (!__all(rm - m_ <= 64.0f)) {    // T13 defer-max (64 z-units = 8 scaled)
      float mn = fmaxf(m_, rm);
      al = __builtin_amdgcn_exp2f((m_ - mn) * C);
      m_ = mn;
#pragma unroll
      for (int j = 0; j < 4; ++j) {
        float alj = __shfl(al, 4 * hi + j, 64);
#pragma unroll
        for (int f = 0; f < 4; ++f) ao[f][j] *= alj;
      }
    }
    float nmc = m_ * -C;
    float rs = 0.f;
#pragma unroll
    for (int n = 0; n < 4; ++n)
#pragma unroll
      for (int j = 0; j < 4; ++j) {
        float pe = __builtin_amdgcn_exp2f(fmaf(z_[n][j], C, nmc));
        z_[n][j] = pe;
        rs += pe;
      }
    rs += __shfl_xor(rs, 16, 64);
    rs += __shfl_xor(rs, 32, 64);
    l_ = l_ * al + rs;
    // pack P -> bf16, vector store to per-wave LDS slice (in-wave RAW ok)
#pragma unroll
    for (int n = 0; n < 4; ++n) {
      unsigned w0, w1;
      asm("v_cvt_pk_bf16_f32 %0, %1, %2" : "=v"(w0) : "v"(z_[n][0]), "v"(z_[n][1]));
      asm("v_cvt_pk_bf16_f32 %0, %1, %2" : "=v"(w1) : "v"(z_[n][2]), "v"(z_[n][3]));
      uint2 pw; pw.x = w0; pw.y = w1;
      *(uint2*)(&lP[w][la][(n * 16 + hi * 4) ^ ((la & 7) << 3)]) = pw;
    }
    {
      const u16* pr = &lP[w][la][0];
      bf16x8 pa0 = *(const bf16x8*)(pr + rcc);
      bf16x8 pa1 = *(const bf16x8*)(pr + (rcc ^ 32));
      __builtin_amdgcn_s_setprio(1);
#pragma unroll
      for (int f = 0; f < 4; ++f) {
        ao[f] = __builtin_amdgcn_mfma_f32_16x16x32_bf16(pa0, v0[f], ao[f], 0, 0, 0);
        ao[f] = __builtin_amdgcn_mfma_f32_16x16x32_bf16(pa1, v1[f], ao[f], 0, 0, 0);
      }
      __builtin_amdgcn_s_setprio(0);
    }
    if (kt + 1 < nt) {                 // write next K tile into other buffer
      *(u16x8*)(&lK[cur ^ 1][sr][sw])      = kreg0;
      *(u16x8*)(&lK[cur ^ 1][sr + 32][sw]) = kreg1;
    }
  }
  // epilogue: O rows q = hi*4+j; l_ lives on lane q -> broadcast
  float linv[4];
#pragma unroll
  for (int j = 0; j < 4; ++j) linv[j] = 1.0f / __shfl(l_, 4 * hi + j, 64);
#pragma unroll
  for (int f = 0; f < 4; ++f)
#pragma unroll
    for (int j = 0; j < 4; ++j) {
      int row = qr0 + hi * 4 + j;
      Ob[((size_t)(b * 2048 + row)) * 1024 + h * 64 + f * 16 + la] = f2b(ao[f][j] * linv[j]);
    }
}

extern "C" void kernel_launch(void* const* d_in, const int* in_sizes, int n_in,
                              void* d_out, int out_size, void* d_ws, size_t ws_size,
                              hipStream_t stream) {
  const float* x  = (const float*)d_in[0];   // (2,2048,1024) f32
  const float* wa = (const float*)d_in[1];   // (1024,1536)  f32
  const float* wp = (const float*)d_in[2];   // (1024,1024)  f32
  float* out = (float*)d_out;                // (2,2048,1024) f32
  char* ws = (char*)d_ws;
  u16* xb    = (u16*)(ws + 0);          // 4096x1024 bf16
  u16* waT   = (u16*)(ws + 8388608);    // 1536x1024 bf16
  u16* wpT   = (u16*)(ws + 11534336);   // 1024x1024 bf16
  u16* qkvb  = (u16*)(ws + 13631488);   // 4096x1536 bf16
  u16* Qb    = (u16*)(ws + 26214400);   // [2][16][2048][64] bf16
  u16* Kb    = (u16*)(ws + 34603008);   // [2][4][2048][64] bf16
  u16* Vtb   = (u16*)(ws + 36700160);   // [2][4][64][2048] bf16
  u16* Ob    = (u16*)(ws + 38797312);   // 4096x1024 bf16
  float2* rt = (float2*)(ws + 47185920); // 2048x32 float2 (512KB)

  k_prep<<<4864, 256, 0, stream>>>(x, wa, wp, xb, waT, wpT, rt);
  k_gemm_bt<1><<<dim3(12, 64), 256, 0, stream>>>(xb, waT, qkvb, 4096, 1536, 1024);
  k_rvt<<<3072, 320, 0, stream>>>(qkvb, rt, Qb, Kb, Vtb);
  k_attn<<<dim3(32, 32), 256, 0, stream>>>(Qb, Kb, Vtb, Ob);
  k_gemm_bt<0><<<dim3(8, 64), 256, 0, stream>>>(Ob, wpT, out, 4096, 1024, 1024);
}

// Round 8
// 90.184 us; speedup vs baseline: 1.3566x; 1.3566x over previous
//
#include <hip/hip_runtime.h>

typedef unsigned short u16;
typedef __attribute__((ext_vector_type(8))) short bf16x8;
typedef __attribute__((ext_vector_type(4))) float f32x4;
typedef __attribute__((ext_vector_type(8))) unsigned short u16x8;
typedef __attribute__((ext_vector_type(4))) unsigned short u16x4;
typedef __attribute__((ext_vector_type(2))) unsigned short u16x2;

// ---- bf16 helpers (RNE) ----
__device__ __forceinline__ u16 f2b(float f) {
  unsigned u = __builtin_bit_cast(unsigned, f);
  unsigned r = (u + 0x7fffu + ((u >> 16) & 1u)) >> 16;
  return (u16)r;
}
__device__ __forceinline__ float b2f(u16 u) {
  return __builtin_bit_cast(float, ((unsigned)u) << 16);
}
__device__ __forceinline__ void gload16(const void* g, void* l) {
  __builtin_amdgcn_global_load_lds(
      (const __attribute__((address_space(1))) unsigned int*)g,
      (__attribute__((address_space(3))) unsigned int*)l, 16, 0, 0);
}

// ---- fused prep: x cast (2048) | waT (1536) | wpT (1024) | rope tab (256) ----
__global__ __launch_bounds__(256) void k_prep(const float* __restrict__ x,
                                              const float* __restrict__ wa,
                                              const float* __restrict__ wp,
                                              u16* __restrict__ xb,
                                              u16* __restrict__ waT,
                                              u16* __restrict__ wpT,
                                              float2* __restrict__ tab) {
  __shared__ float t[32][33];
  const int idx = blockIdx.x;
  const int tid = threadIdx.x;
  if (idx < 2048) {                       // cast x -> bf16, 8 elems/thread
    int i = idx * 256 + tid;
    float4 v0 = ((const float4*)x)[i * 2];
    float4 v1 = ((const float4*)x)[i * 2 + 1];
    u16x8 o;
    o[0] = f2b(v0.x); o[1] = f2b(v0.y); o[2] = f2b(v0.z); o[3] = f2b(v0.w);
    o[4] = f2b(v1.x); o[5] = f2b(v1.y); o[6] = f2b(v1.z); o[7] = f2b(v1.w);
    ((u16x8*)xb)[i] = o;
    return;
  }
  const int tx = tid & 31, ty = tid >> 5; // transpose tiles, block as (32,8)
  if (idx < 3584) {                       // waT: (1024 x 1536) -> (1536 x 1024)
    int tt = idx - 2048;
    int c0 = (tt % 48) * 32, r0 = (tt / 48) * 32;
    for (int ii = 0; ii < 4; ++ii)
      t[ty + ii * 8][tx] = wa[(size_t)(r0 + ty + ii * 8) * 1536 + c0 + tx];
    __syncthreads();
    for (int ii = 0; ii < 4; ++ii)
      waT[(size_t)(c0 + ty + ii * 8) * 1024 + r0 + tx] = f2b(t[tx][ty + ii * 8]);
    return;
  }
  if (idx < 4608) {                       // wpT: (1024 x 1024) -> (1024 x 1024)
    int tt = idx - 3584;
    int c0 = (tt & 31) * 32, r0 = (tt >> 5) * 32;
    for (int ii = 0; ii < 4; ++ii)
      t[ty + ii * 8][tx] = wp[(size_t)(r0 + ty + ii * 8) * 1024 + c0 + tx];
    __syncthreads();
    for (int ii = 0; ii < 4; ++ii)
      wpT[(size_t)(c0 + ty + ii * 8) * 1024 + r0 + tx] = f2b(t[tx][ty + ii * 8]);
    return;
  }
  {                                       // rope table
    int e = (idx - 4608) * 256 + tid;     // 65536 entries
    int tt = e >> 5, i = e & 31;
    float inv = expf((float)(2 * i) * -0.14391156831f);
    float fr = (float)tt * inv;
    float s, c;
    sincosf(fr, &s, &c);
    tab[tt * 32 + i] = make_float2(c, s);
  }
}

// ---- GEMM: C[M,N] = A[M,K](bf16,row) * Bt[N,K](bf16,row) ----
// 64x128 tile, BK=64, 4 waves 2x2, XOR-swizzled LDS (rule 21).
template<int OUT_BF16>
__global__ __launch_bounds__(256) void k_gemm_bt(const u16* __restrict__ A,
                                                 const u16* __restrict__ Bt,
                                                 void* __restrict__ Cv,
                                                 int M, int N, int K) {
  __shared__ u16 lA[64 * 64];
  __shared__ u16 lB[128 * 64];
  const int tid = threadIdx.x;
  const int lane = tid & 63, w = tid >> 6;
  const int wr = w >> 1, wc = w & 1;
  const int la = lane & 15, hi = lane >> 4;
  const int bm0 = blockIdx.y * 64, bn0 = blockIdx.x * 128;
  const f32x4 zero = {0.f, 0.f, 0.f, 0.f};
  f32x4 acc[2][4];
#pragma unroll
  for (int m = 0; m < 2; ++m)
#pragma unroll
    for (int n = 0; n < 4; ++n) acc[m][n] = zero;

  const int r = tid >> 3;           // staging row within round (0..31)
  const int s = tid & 7;            // staging slot
  for (int k0 = 0; k0 < K; k0 += 64) {
#pragma unroll
    for (int rr = 0; rr < 2; ++rr) {
      int row = rr * 32 + r;
      gload16(A + (size_t)(bm0 + row) * K + k0 + ((s ^ (row & 7)) << 3),
              &lA[(rr * 256 + tid) * 8]);
    }
#pragma unroll
    for (int rr = 0; rr < 4; ++rr) {
      int row = rr * 32 + r;
      gload16(Bt + (size_t)(bn0 + row) * K + k0 + ((s ^ (row & 7)) << 3),
              &lB[(rr * 256 + tid) * 8]);
    }
    __syncthreads();
#pragma unroll
    for (int kk = 0; kk < 2; ++kk) {
      bf16x8 af[2], bfr[4];
#pragma unroll
      for (int m = 0; m < 2; ++m) {
        int R = wr * 32 + m * 16 + la;
        af[m] = *(const bf16x8*)&lA[R * 64 + (((kk * 4 + hi) ^ (R & 7)) << 3)];
      }
#pragma unroll
      for (int n = 0; n < 4; ++n) {
        int R = wc * 64 + n * 16 + la;
        bfr[n] = *(const bf16x8*)&lB[R * 64 + (((kk * 4 + hi) ^ (R & 7)) << 3)];
      }
#pragma unroll
      for (int m = 0; m < 2; ++m)
#pragma unroll
        for (int n = 0; n < 4; ++n)
          acc[m][n] = __builtin_amdgcn_mfma_f32_16x16x32_bf16(af[m], bfr[n], acc[m][n], 0, 0, 0);
    }
    __syncthreads();
  }
  float* Cf = (float*)Cv;
  u16*   Cb = (u16*)Cv;
#pragma unroll
  for (int m = 0; m < 2; ++m)
#pragma unroll
    for (int n = 0; n < 4; ++n)
#pragma unroll
      for (int j = 0; j < 4; ++j) {
        int row = bm0 + wr * 32 + m * 16 + hi * 4 + j;
        int col = bn0 + wc * 64 + n * 16 + la;
        float v = acc[m][n][j];
        if (OUT_BF16) Cb[(size_t)row * N + col] = f2b(v);
        else          Cf[(size_t)row * N + col] = v;
      }
}

// ---- fused rope_rms (2048 blocks, 2 rows each) + V transpose (1024) ----
__global__ __launch_bounds__(320) void k_rvt(const u16* __restrict__ qkv,
                                             const float2* __restrict__ tab,
                                             u16* __restrict__ Qb,
                                             u16* __restrict__ Kb,
                                             u16* __restrict__ Vt) {
  const int idx = blockIdx.x;
  const int tid = threadIdx.x;
  if (idx < 2048) {                     // rope+rms: 2 rows, 160 threads each
    const int half = (tid >= 160);
    const int lt = tid - half * 160;
    const int row = idx * 2 + half;     // b*T + t
    const int hh = lt >> 3, s = lt & 7;
    const int b = row >> 11, t = row & 2047;
    const int col = (hh < 16) ? hh * 64 : 1024 + (hh - 16) * 64;
    u16x8 xv = *(const u16x8*)(qkv + (size_t)row * 1536 + col + s * 8);
    float4 c01 = *(const float4*)(tab + t * 32 + s * 4);
    float4 c23 = *(const float4*)(tab + t * 32 + s * 4 + 2);
    float y[8];
    {
      float x0 = b2f(xv[0]), x1 = b2f(xv[1]);
      y[0] = x0 * c01.x - x1 * c01.y; y[1] = x1 * c01.x + x0 * c01.y;
      x0 = b2f(xv[2]); x1 = b2f(xv[3]);
      y[2] = x0 * c01.z - x1 * c01.w; y[3] = x1 * c01.z + x0 * c01.w;
      x0 = b2f(xv[4]); x1 = b2f(xv[5]);
      y[4] = x0 * c23.x - x1 * c23.y; y[5] = x1 * c23.x + x0 * c23.y;
      x0 = b2f(xv[6]); x1 = b2f(xv[7]);
      y[6] = x0 * c23.z - x1 * c23.w; y[7] = x1 * c23.z + x0 * c23.w;
    }
    float ss = 0.f;
#pragma unroll
    for (int e = 0; e < 8; ++e) ss += y[e] * y[e];
    ss += __shfl_xor(ss, 1, 8);
    ss += __shfl_xor(ss, 2, 8);
    ss += __shfl_xor(ss, 4, 8);
    float sc = rsqrtf(ss * (1.0f / 64.0f) + 1e-6f);
    u16x8 o;
#pragma unroll
    for (int e = 0; e < 8; ++e) o[e] = f2b(y[e] * sc);
    size_t ob;
    u16* outp;
    if (hh < 16) { outp = Qb; ob = ((size_t)((b * 16 + hh) * 2048 + t)) * 64 + s * 8; }
    else         { outp = Kb; ob = ((size_t)((b * 4 + hh - 16) * 2048 + t)) * 64 + s * 8; }
    *(u16x8*)(outp + ob) = o;
    return;
  }
  // V transpose: 1024 tile-blocks, threads 0..255 as (32,8)
  __shared__ u16 t[32][33];
  if (tid >= 256) return;
  const int ii2 = idx - 2048;
  const int bg = ii2 >> 7;              // 0..7
  const int b = bg >> 2, g = bg & 3;
  const int t0 = (ii2 & 63) * 32, d0 = ((ii2 >> 6) & 1) * 32;
  const int tx = tid & 31, ty = tid >> 5;
  const u16* src = qkv + (size_t)b * 2048 * 1536 + 1280 + g * 64;
  for (int ii = 0; ii < 4; ++ii)
    t[ty + ii * 8][tx] = src[(size_t)(t0 + ty + ii * 8) * 1536 + d0 + tx];
  __syncthreads();
  u16* dst = Vt + (size_t)bg * 64 * 2048;
  for (int ii = 0; ii < 4; ++ii)
    dst[(size_t)(d0 + ty + ii * 8) * 2048 + t0 + tx] = t[tx][ty + ii * 8];
}

// ---- causal GQA flash attention, v7 (fixed-max softmax) ----
// grid (32 bh, 32 qtiles), block 256 (4 waves x 16 q-rows).
// RMS-normed q,k => |q|=|k|=8 => z = q.k in [-64,64]; softmax uses the
// CONSTANT max 64: p = exp2(fma(z, C, -64C)). No row-max reduce, no
// rescale, no per-iter cross-lane ops; l accumulated per-lane, reduced
// once in the epilogue. K/V double-buffered swizzled LDS, one barrier
// per tile, prefetch ISSUED AFTER the barrier (drains at trailing
// ds_write, never at the barrier).
__global__ __launch_bounds__(256, 4) void k_attn(const u16* __restrict__ Qb,
                                                 const u16* __restrict__ Kb,
                                                 const u16* __restrict__ Vtb,
                                                 u16* __restrict__ Ob) {
  __shared__ u16 lK[2][64][64];
  __shared__ u16 lVt[2][64][64];
  __shared__ u16 lP[4][16][64];
  const int bh = blockIdx.x;
  const int b = bh >> 4, h = bh & 15, g = h >> 2;
  const int y = blockIdx.y;
  // per-CU balanced qtile map: streams {a, a+8, a+16, a+24}
  const int qtile = (y < 8) ? 31 - y : (y < 16) ? y + 8 : (y < 24) ? 31 - y : y - 24;
  const int tid = threadIdx.x;
  const int lane = tid & 63, w = tid >> 6;
  const int la = lane & 15, hi = lane >> 4;
  const int qr0 = qtile * 64 + w * 16;
  const int nt = qtile + 1;

  const u16* Qg  = Qb  + (size_t)(b * 16 + h) * 2048 * 64;
  const u16* Kg  = Kb  + (size_t)(b * 4 + g) * 2048 * 64;
  const u16* Vtg = Vtb + (size_t)(b * 4 + g) * 64 * 2048;

  bf16x8 qf0, qf1;
  {
    const u16* ptr = Qg + (size_t)(qr0 + la) * 64 + hi * 8;
    qf0 = *(const bf16x8*)ptr;
    qf1 = *(const bf16x8*)(ptr + 32);
  }
  const float C = 0.18033688011f;      // 0.125 * log2(e)
  const float nmc = -64.0f * C;        // fixed max (64 z-units = 8 scaled)
  float l_ = 0.f;
  const f32x4 zero = {0.f, 0.f, 0.f, 0.f};
  f32x4 ao[4];
#pragma unroll
  for (int f = 0; f < 4; ++f) ao[f] = zero;

  const int sr = tid >> 3;             // staging row 0..31 (and +32)
  const int ss = (tid & 7) * 8;        // u16 col of the 16B chunk
  const int sw = ss ^ ((sr & 7) << 3); // swizzled LDS col
  const int rcc = (hi * 8) ^ ((la & 7) << 3);  // swizzled read col

  {                                    // prologue: stage tile 0
    u16x8 k0 = *(const u16x8*)(Kg  + (size_t)sr * 64 + ss);
    u16x8 k1 = *(const u16x8*)(Kg  + (size_t)(sr + 32) * 64 + ss);
    u16x8 q0 = *(const u16x8*)(Vtg + (size_t)sr * 2048 + ss);
    u16x8 q1 = *(const u16x8*)(Vtg + (size_t)(sr + 32) * 2048 + ss);
    *(u16x8*)(&lK[0][sr][sw])       = k0;
    *(u16x8*)(&lK[0][sr + 32][sw])  = k1;
    *(u16x8*)(&lVt[0][sr][sw])      = q0;
    *(u16x8*)(&lVt[0][sr + 32][sw]) = q1;
  }

  for (int kt = 0; kt < nt; ++kt) {
    const int cur = kt & 1;
    __syncthreads();                   // buf[cur] ready (written last iter)

    // issue next-tile loads AFTER the barrier (drain at trailing ds_write)
    u16x8 kreg0, kreg1, vreg0, vreg1;
    if (kt + 1 < nt) {
      int kv = (kt + 1) * 64;
      kreg0 = *(const u16x8*)(Kg  + (size_t)(kv + sr) * 64 + ss);
      kreg1 = *(const u16x8*)(Kg  + (size_t)(kv + sr + 32) * 64 + ss);
      vreg0 = *(const u16x8*)(Vtg + (size_t)sr * 2048 + kv + ss);
      vreg1 = *(const u16x8*)(Vtg + (size_t)(sr + 32) * 2048 + kv + ss);
    }

    // S^T = K Q^T: lane -> q=la, kv = n*16 + hi*4 + j (raw z units)
    float z_[4][4];
    __builtin_amdgcn_s_setprio(1);
#pragma unroll
    for (int n = 0; n < 4; ++n) {
      const u16* kr = &lK[cur][n * 16 + la][0];
      bf16x8 kb0 = *(const bf16x8*)(kr + rcc);
      bf16x8 kb1 = *(const bf16x8*)(kr + (rcc ^ 32));
      f32x4 z = zero;
      z = __builtin_amdgcn_mfma_f32_16x16x32_bf16(kb0, qf0, z, 0, 0, 0);
      z = __builtin_amdgcn_mfma_f32_16x16x32_bf16(kb1, qf1, z, 0, 0, 0);
#pragma unroll
      for (int j = 0; j < 4; ++j) z_[n][j] = z[j];
    }
    __builtin_amdgcn_s_setprio(0);
    if (kt == nt - 1) {                // diagonal tile: causal mask
#pragma unroll
      for (int n = 0; n < 4; ++n)
#pragma unroll
        for (int j = 0; j < 4; ++j)
          if (n * 16 + hi * 4 + j > w * 16 + la) z_[n][j] = -3e38f;
    }
    // fixed-max softmax: pure elementwise, l off the critical path
    float rs = 0.f;
#pragma unroll
    for (int n = 0; n < 4; ++n)
#pragma unroll
      for (int j = 0; j < 4; ++j) {
        float pe = __builtin_amdgcn_exp2f(fmaf(z_[n][j], C, nmc));
        z_[n][j] = pe;
        rs += pe;
      }
    l_ += rs;
    // pack P -> bf16, vector store to per-wave LDS slice (in-wave RAW ok)
#pragma unroll
    for (int n = 0; n < 4; ++n) {
      unsigned w0, w1;
      asm("v_cvt_pk_bf16_f32 %0, %1, %2" : "=v"(w0) : "v"(z_[n][0]), "v"(z_[n][1]));
      asm("v_cvt_pk_bf16_f32 %0, %1, %2" : "=v"(w1) : "v"(z_[n][2]), "v"(z_[n][3]));
      uint2 pw; pw.x = w0; pw.y = w1;
      *(uint2*)(&lP[w][la][(n * 16 + hi * 4) ^ ((la & 7) << 3)]) = pw;
    }
    {
      const u16* pr = &lP[w][la][0];
      bf16x8 pa0 = *(const bf16x8*)(pr + rcc);
      bf16x8 pa1 = *(const bf16x8*)(pr + (rcc ^ 32));
      __builtin_amdgcn_s_setprio(1);
#pragma unroll
      for (int f = 0; f < 4; ++f) {
        const u16* vr = &lVt[cur][f * 16 + la][0];
        bf16x8 v0 = *(const bf16x8*)(vr + rcc);
        bf16x8 v1 = *(const bf16x8*)(vr + (rcc ^ 32));
        ao[f] = __builtin_amdgcn_mfma_f32_16x16x32_bf16(pa0, v0, ao[f], 0, 0, 0);
        ao[f] = __builtin_amdgcn_mfma_f32_16x16x32_bf16(pa1, v1, ao[f], 0, 0, 0);
      }
      __builtin_amdgcn_s_setprio(0);
    }
    if (kt + 1 < nt) {                 // write next tile into other buffer
      const int nxt = cur ^ 1;
      *(u16x8*)(&lK[nxt][sr][sw])       = kreg0;
      *(u16x8*)(&lK[nxt][sr + 32][sw])  = kreg1;
      *(u16x8*)(&lVt[nxt][sr][sw])      = vreg0;
      *(u16x8*)(&lVt[nxt][sr + 32][sw]) = vreg1;
    }
  }
  // epilogue: reduce l across the 4 hi-copies ONCE, then normalize
  l_ += __shfl_xor(l_, 16, 64);
  l_ += __shfl_xor(l_, 32, 64);
  float linv[4];
#pragma unroll
  for (int j = 0; j < 4; ++j) linv[j] = 1.0f / __shfl(l_, 4 * hi + j, 64);
#pragma unroll
  for (int f = 0; f < 4; ++f)
#pragma unroll
    for (int j = 0; j < 4; ++j) {
      int row = qr0 + hi * 4 + j;
      Ob[((size_t)(b * 2048 + row)) * 1024 + h * 64 + f * 16 + la] = f2b(ao[f][j] * linv[j]);
    }
}

extern "C" void kernel_launch(void* const* d_in, const int* in_sizes, int n_in,
                              void* d_out, int out_size, void* d_ws, size_t ws_size,
                              hipStream_t stream) {
  const float* x  = (const float*)d_in[0];   // (2,2048,1024) f32
  const float* wa = (const float*)d_in[1];   // (1024,1536)  f32
  const float* wp = (const float*)d_in[2];   // (1024,1024)  f32
  float* out = (float*)d_out;                // (2,2048,1024) f32
  char* ws = (char*)d_ws;
  u16* xb    = (u16*)(ws + 0);          // 4096x1024 bf16
  u16* waT   = (u16*)(ws + 8388608);    // 1536x1024 bf16
  u16* wpT   = (u16*)(ws + 11534336);   // 1024x1024 bf16
  u16* qkvb  = (u16*)(ws + 13631488);   // 4096x1536 bf16
  u16* Qb    = (u16*)(ws + 26214400);   // [2][16][2048][64] bf16
  u16* Kb    = (u16*)(ws + 34603008);   // [2][4][2048][64] bf16
  u16* Vtb   = (u16*)(ws + 36700160);   // [2][4][64][2048] bf16
  u16* Ob    = (u16*)(ws + 38797312);   // 4096x1024 bf16
  float2* rt = (float2*)(ws + 47185920); // 2048x32 float2 (512KB)

  k_prep<<<4864, 256, 0, stream>>>(x, wa, wp, xb, waT, wpT, rt);
  k_gemm_bt<1><<<dim3(12, 64), 256, 0, stream>>>(xb, waT, qkvb, 4096, 1536, 1024);
  k_rvt<<<3072, 320, 0, stream>>>(qkvb, rt, Qb, Kb, Vtb);
  k_attn<<<dim3(32, 32), 256, 0, stream>>>(Qb, Kb, Vtb, Ob);
  k_gemm_bt<0><<<dim3(8, 64), 256, 0, stream>>>(Ob, wpT, out, 4096, 1024, 1024);
}

// Round 9
// 86.494 us; speedup vs baseline: 1.4145x; 1.0427x over previous
//
#include <hip/hip_runtime.h>

typedef unsigned short u16;
typedef __attribute__((ext_vector_type(8))) short bf16x8;
typedef __attribute__((ext_vector_type(4))) float f32x4;
typedef __attribute__((ext_vector_type(8))) unsigned short u16x8;
typedef __attribute__((ext_vector_type(4))) unsigned short u16x4;
typedef __attribute__((ext_vector_type(2))) unsigned short u16x2;

// ---- bf16 helpers (RNE) ----
__device__ __forceinline__ u16 f2b(float f) {
  unsigned u = __builtin_bit_cast(unsigned, f);
  unsigned r = (u + 0x7fffu + ((u >> 16) & 1u)) >> 16;
  return (u16)r;
}
__device__ __forceinline__ float b2f(u16 u) {
  return __builtin_bit_cast(float, ((unsigned)u) << 16);
}
__device__ __forceinline__ void gload16(const void* g, void* l) {
  __builtin_amdgcn_global_load_lds(
      (const __attribute__((address_space(1))) unsigned int*)g,
      (__attribute__((address_space(3))) unsigned int*)l, 16, 0, 0);
}

// ---- fused prep: x cast (2048) | waT (1536) | wpT (1024) | rope tab (256) ----
__global__ __launch_bounds__(256) void k_prep(const float* __restrict__ x,
                                              const float* __restrict__ wa,
                                              const float* __restrict__ wp,
                                              u16* __restrict__ xb,
                                              u16* __restrict__ waT,
                                              u16* __restrict__ wpT,
                                              float2* __restrict__ tab) {
  __shared__ float t[32][33];
  const int idx = blockIdx.x;
  const int tid = threadIdx.x;
  if (idx < 2048) {                       // cast x -> bf16, 8 elems/thread
    int i = idx * 256 + tid;
    float4 v0 = ((const float4*)x)[i * 2];
    float4 v1 = ((const float4*)x)[i * 2 + 1];
    u16x8 o;
    o[0] = f2b(v0.x); o[1] = f2b(v0.y); o[2] = f2b(v0.z); o[3] = f2b(v0.w);
    o[4] = f2b(v1.x); o[5] = f2b(v1.y); o[6] = f2b(v1.z); o[7] = f2b(v1.w);
    ((u16x8*)xb)[i] = o;
    return;
  }
  const int tx = tid & 31, ty = tid >> 5; // transpose tiles, block as (32,8)
  if (idx < 3584) {                       // waT: (1024 x 1536) -> (1536 x 1024)
    int tt = idx - 2048;
    int c0 = (tt % 48) * 32, r0 = (tt / 48) * 32;
    for (int ii = 0; ii < 4; ++ii)
      t[ty + ii * 8][tx] = wa[(size_t)(r0 + ty + ii * 8) * 1536 + c0 + tx];
    __syncthreads();
    for (int ii = 0; ii < 4; ++ii)
      waT[(size_t)(c0 + ty + ii * 8) * 1024 + r0 + tx] = f2b(t[tx][ty + ii * 8]);
    return;
  }
  if (idx < 4608) {                       // wpT: (1024 x 1024) -> (1024 x 1024)
    int tt = idx - 3584;
    int c0 = (tt & 31) * 32, r0 = (tt >> 5) * 32;
    for (int ii = 0; ii < 4; ++ii)
      t[ty + ii * 8][tx] = wp[(size_t)(r0 + ty + ii * 8) * 1024 + c0 + tx];
    __syncthreads();
    for (int ii = 0; ii < 4; ++ii)
      wpT[(size_t)(c0 + ty + ii * 8) * 1024 + r0 + tx] = f2b(t[tx][ty + ii * 8]);
    return;
  }
  {                                       // rope table
    int e = (idx - 4608) * 256 + tid;     // 65536 entries
    int tt = e >> 5, i = e & 31;
    float inv = expf((float)(2 * i) * -0.14391156831f);
    float fr = (float)tt * inv;
    float s, c;
    sincosf(fr, &s, &c);
    tab[tt * 32 + i] = make_float2(c, s);
  }
}

// ---- GEMM1 + fused rope/rms/V-transpose epilogue ----
// C = xb[4096,1024] * waT[1536,1024]^T, tile 64x128, BK=64, swizzled LDS.
// bx<8: q heads (rope+rms -> Qb); bx 8,9: k heads (-> Kb); bx 10,11: v
// (plain bf16, transposed via reused LDS -> Vtb[bg][64][2048]).
__global__ __launch_bounds__(256) void k_gemm1(const u16* __restrict__ A,
                                               const u16* __restrict__ Bt,
                                               const float2* __restrict__ tab,
                                               u16* __restrict__ Qb,
                                               u16* __restrict__ Kb,
                                               u16* __restrict__ Vtb) {
  __shared__ u16 smem[64 * 64 + 128 * 64];   // lA | lB; reused as vbuf
  u16* lA = smem;
  u16* lB = smem + 64 * 64;
  const int tid = threadIdx.x;
  const int lane = tid & 63, w = tid >> 6;
  const int wr = w >> 1, wc = w & 1;
  const int la = lane & 15, hi = lane >> 4;
  const int bx = blockIdx.x;
  const int bm0 = blockIdx.y * 64, bn0 = bx * 128;
  const int K = 1024;
  const f32x4 zero = {0.f, 0.f, 0.f, 0.f};
  f32x4 acc[2][4];
#pragma unroll
  for (int m = 0; m < 2; ++m)
#pragma unroll
    for (int n = 0; n < 4; ++n) acc[m][n] = zero;

  const int r = tid >> 3;
  const int s = tid & 7;
  for (int k0 = 0; k0 < K; k0 += 64) {
#pragma unroll
    for (int rr = 0; rr < 2; ++rr) {
      int row = rr * 32 + r;
      gload16(A + (size_t)(bm0 + row) * K + k0 + ((s ^ (row & 7)) << 3),
              &lA[(rr * 256 + tid) * 8]);
    }
#pragma unroll
    for (int rr = 0; rr < 4; ++rr) {
      int row = rr * 32 + r;
      gload16(Bt + (size_t)(bn0 + row) * K + k0 + ((s ^ (row & 7)) << 3),
              &lB[(rr * 256 + tid) * 8]);
    }
    __syncthreads();
#pragma unroll
    for (int kk = 0; kk < 2; ++kk) {
      bf16x8 af[2], bfr[4];
#pragma unroll
      for (int m = 0; m < 2; ++m) {
        int R = wr * 32 + m * 16 + la;
        af[m] = *(const bf16x8*)&lA[R * 64 + (((kk * 4 + hi) ^ (R & 7)) << 3)];
      }
#pragma unroll
      for (int n = 0; n < 4; ++n) {
        int R = wc * 64 + n * 16 + la;
        bfr[n] = *(const bf16x8*)&lB[R * 64 + (((kk * 4 + hi) ^ (R & 7)) << 3)];
      }
#pragma unroll
      for (int m = 0; m < 2; ++m)
#pragma unroll
        for (int n = 0; n < 4; ++n)
          acc[m][n] = __builtin_amdgcn_mfma_f32_16x16x32_bf16(af[m], bfr[n], acc[m][n], 0, 0, 0);
    }
    __syncthreads();
  }
  // ---- fused epilogue ----
  const int tloc = bm0 & 2047;
  const int bb = bm0 >> 11;
  if (bx < 10) {
    const int isq = (bx < 8);
    const int head = isq ? (2 * bx + wc) : (2 * (bx - 8) + wc);
    u16* outp = isq ? Qb : Kb;
    const size_t hbase = ((size_t)(bb * (isq ? 16 : 4) + head) * 2048) * 64;
    const int odd = la & 1;
#pragma unroll
    for (int m = 0; m < 2; ++m)
#pragma unroll
      for (int j = 0; j < 4; ++j) {
        const int tr = tloc + wr * 32 + m * 16 + hi * 4 + j;
        const float2* tb = tab + tr * 32 + (la >> 1);
        float y[4], ssl = 0.f;
#pragma unroll
        for (int n = 0; n < 4; ++n) {
          float v = acc[m][n][j];
          float p = __shfl_xor(v, 1);
          float2 cs = tb[n * 8];
          y[n] = odd ? fmaf(v, cs.x, p * cs.y)
                     : fmaf(v, cs.x, -p * cs.y);
          ssl = fmaf(y[n], y[n], ssl);
        }
        ssl += __shfl_xor(ssl, 1);
        ssl += __shfl_xor(ssl, 2);
        ssl += __shfl_xor(ssl, 4);
        ssl += __shfl_xor(ssl, 8);
        const float sc = rsqrtf(ssl * (1.0f / 64.0f) + 1e-6f);
        u16* rp = outp + hbase + (size_t)tr * 64 + la;
#pragma unroll
        for (int n = 0; n < 4; ++n) rp[n * 16] = f2b(y[n] * sc);
      }
  } else {
    // V block: bf16 into vbuf[64][132] (reuses lA/lB), transposed write
    u16* vbuf = smem;
#pragma unroll
    for (int m = 0; m < 2; ++m)
#pragma unroll
      for (int n = 0; n < 4; ++n)
#pragma unroll
        for (int j = 0; j < 4; ++j)
          vbuf[(wr * 32 + m * 16 + hi * 4 + j) * 132 + wc * 64 + n * 16 + la] =
              f2b(acc[m][n][j]);
    __syncthreads();
    const int dloc = tid >> 1, th = tid & 1;
    const int g = 2 * (bx - 10) + (dloc >> 6);
    const int d = dloc & 63;
    u16* dst = Vtb + ((size_t)(bb * 4 + g) * 64 + d) * 2048 + tloc + th * 32;
#pragma unroll
    for (int c = 0; c < 4; ++c) {
      u16x8 o;
#pragma unroll
      for (int e = 0; e < 8; ++e) o[e] = vbuf[(th * 32 + c * 8 + e) * 132 + dloc];
      *(u16x8*)(dst + c * 8) = o;
    }
  }
}

// ---- GEMM2: C[M,N] f32 = A[M,K](bf16) * Bt[N,K](bf16) ----
template<int OUT_BF16>
__global__ __launch_bounds__(256) void k_gemm_bt(const u16* __restrict__ A,
                                                 const u16* __restrict__ Bt,
                                                 void* __restrict__ Cv,
                                                 int M, int N, int K) {
  __shared__ u16 lA[64 * 64];
  __shared__ u16 lB[128 * 64];
  const int tid = threadIdx.x;
  const int lane = tid & 63, w = tid >> 6;
  const int wr = w >> 1, wc = w & 1;
  const int la = lane & 15, hi = lane >> 4;
  const int bm0 = blockIdx.y * 64, bn0 = blockIdx.x * 128;
  const f32x4 zero = {0.f, 0.f, 0.f, 0.f};
  f32x4 acc[2][4];
#pragma unroll
  for (int m = 0; m < 2; ++m)
#pragma unroll
    for (int n = 0; n < 4; ++n) acc[m][n] = zero;

  const int r = tid >> 3;
  const int s = tid & 7;
  for (int k0 = 0; k0 < K; k0 += 64) {
#pragma unroll
    for (int rr = 0; rr < 2; ++rr) {
      int row = rr * 32 + r;
      gload16(A + (size_t)(bm0 + row) * K + k0 + ((s ^ (row & 7)) << 3),
              &lA[(rr * 256 + tid) * 8]);
    }
#pragma unroll
    for (int rr = 0; rr < 4; ++rr) {
      int row = rr * 32 + r;
      gload16(Bt + (size_t)(bn0 + row) * K + k0 + ((s ^ (row & 7)) << 3),
              &lB[(rr * 256 + tid) * 8]);
    }
    __syncthreads();
#pragma unroll
    for (int kk = 0; kk < 2; ++kk) {
      bf16x8 af[2], bfr[4];
#pragma unroll
      for (int m = 0; m < 2; ++m) {
        int R = wr * 32 + m * 16 + la;
        af[m] = *(const bf16x8*)&lA[R * 64 + (((kk * 4 + hi) ^ (R & 7)) << 3)];
      }
#pragma unroll
      for (int n = 0; n < 4; ++n) {
        int R = wc * 64 + n * 16 + la;
        bfr[n] = *(const bf16x8*)&lB[R * 64 + (((kk * 4 + hi) ^ (R & 7)) << 3)];
      }
#pragma unroll
      for (int m = 0; m < 2; ++m)
#pragma unroll
        for (int n = 0; n < 4; ++n)
          acc[m][n] = __builtin_amdgcn_mfma_f32_16x16x32_bf16(af[m], bfr[n], acc[m][n], 0, 0, 0);
    }
    __syncthreads();
  }
  float* Cf = (float*)Cv;
  u16*   Cb = (u16*)Cv;
#pragma unroll
  for (int m = 0; m < 2; ++m)
#pragma unroll
    for (int n = 0; n < 4; ++n)
#pragma unroll
      for (int j = 0; j < 4; ++j) {
        int row = bm0 + wr * 32 + m * 16 + hi * 4 + j;
        int col = bn0 + wc * 64 + n * 16 + la;
        float v = acc[m][n][j];
        if (OUT_BF16) Cb[(size_t)row * N + col] = f2b(v);
        else          Cf[(size_t)row * N + col] = v;
      }
}

// ---- causal GQA flash attention, v7 (fixed-max softmax) ----
__global__ __launch_bounds__(256, 4) void k_attn(const u16* __restrict__ Qb,
                                                 const u16* __restrict__ Kb,
                                                 const u16* __restrict__ Vtb,
                                                 u16* __restrict__ Ob) {
  __shared__ u16 lK[2][64][64];
  __shared__ u16 lVt[2][64][64];
  __shared__ u16 lP[4][16][64];
  const int bh = blockIdx.x;
  const int b = bh >> 4, h = bh & 15, g = h >> 2;
  const int y = blockIdx.y;
  const int qtile = (y < 8) ? 31 - y : (y < 16) ? y + 8 : (y < 24) ? 31 - y : y - 24;
  const int tid = threadIdx.x;
  const int lane = tid & 63, w = tid >> 6;
  const int la = lane & 15, hi = lane >> 4;
  const int qr0 = qtile * 64 + w * 16;
  const int nt = qtile + 1;

  const u16* Qg  = Qb  + (size_t)(b * 16 + h) * 2048 * 64;
  const u16* Kg  = Kb  + (size_t)(b * 4 + g) * 2048 * 64;
  const u16* Vtg = Vtb + (size_t)(b * 4 + g) * 64 * 2048;

  bf16x8 qf0, qf1;
  {
    const u16* ptr = Qg + (size_t)(qr0 + la) * 64 + hi * 8;
    qf0 = *(const bf16x8*)ptr;
    qf1 = *(const bf16x8*)(ptr + 32);
  }
  const float C = 0.18033688011f;      // 0.125 * log2(e)
  const float nmc = -64.0f * C;        // fixed max (|q|=|k|=8 after RMS)
  float l_ = 0.f;
  const f32x4 zero = {0.f, 0.f, 0.f, 0.f};
  f32x4 ao[4];
#pragma unroll
  for (int f = 0; f < 4; ++f) ao[f] = zero;

  const int sr = tid >> 3;
  const int ss = (tid & 7) * 8;
  const int sw = ss ^ ((sr & 7) << 3);
  const int rcc = (hi * 8) ^ ((la & 7) << 3);

  {                                    // prologue: stage tile 0
    u16x8 k0 = *(const u16x8*)(Kg  + (size_t)sr * 64 + ss);
    u16x8 k1 = *(const u16x8*)(Kg  + (size_t)(sr + 32) * 64 + ss);
    u16x8 q0 = *(const u16x8*)(Vtg + (size_t)sr * 2048 + ss);
    u16x8 q1 = *(const u16x8*)(Vtg + (size_t)(sr + 32) * 2048 + ss);
    *(u16x8*)(&lK[0][sr][sw])       = k0;
    *(u16x8*)(&lK[0][sr + 32][sw])  = k1;
    *(u16x8*)(&lVt[0][sr][sw])      = q0;
    *(u16x8*)(&lVt[0][sr + 32][sw]) = q1;
  }

  for (int kt = 0; kt < nt; ++kt) {
    const int cur = kt & 1;
    __syncthreads();

    u16x8 kreg0, kreg1, vreg0, vreg1;
    if (kt + 1 < nt) {
      int kv = (kt + 1) * 64;
      kreg0 = *(const u16x8*)(Kg  + (size_t)(kv + sr) * 64 + ss);
      kreg1 = *(const u16x8*)(Kg  + (size_t)(kv + sr + 32) * 64 + ss);
      vreg0 = *(const u16x8*)(Vtg + (size_t)sr * 2048 + kv + ss);
      vreg1 = *(const u16x8*)(Vtg + (size_t)(sr + 32) * 2048 + kv + ss);
    }

    float z_[4][4];
    __builtin_amdgcn_s_setprio(1);
#pragma unroll
    for (int n = 0; n < 4; ++n) {
      const u16* kr = &lK[cur][n * 16 + la][0];
      bf16x8 kb0 = *(const bf16x8*)(kr + rcc);
      bf16x8 kb1 = *(const bf16x8*)(kr + (rcc ^ 32));
      f32x4 z = zero;
      z = __builtin_amdgcn_mfma_f32_16x16x32_bf16(kb0, qf0, z, 0, 0, 0);
      z = __builtin_amdgcn_mfma_f32_16x16x32_bf16(kb1, qf1, z, 0, 0, 0);
#pragma unroll
      for (int j = 0; j < 4; ++j) z_[n][j] = z[j];
    }
    __builtin_amdgcn_s_setprio(0);
    if (kt == nt - 1) {
#pragma unroll
      for (int n = 0; n < 4; ++n)
#pragma unroll
        for (int j = 0; j < 4; ++j)
          if (n * 16 + hi * 4 + j > w * 16 + la) z_[n][j] = -3e38f;
    }
    float rs = 0.f;
#pragma unroll
    for (int n = 0; n < 4; ++n)
#pragma unroll
      for (int j = 0; j < 4; ++j) {
        float pe = __builtin_amdgcn_exp2f(fmaf(z_[n][j], C, nmc));
        z_[n][j] = pe;
        rs += pe;
      }
    l_ += rs;
#pragma unroll
    for (int n = 0; n < 4; ++n) {
      unsigned w0, w1;
      asm("v_cvt_pk_bf16_f32 %0, %1, %2" : "=v"(w0) : "v"(z_[n][0]), "v"(z_[n][1]));
      asm("v_cvt_pk_bf16_f32 %0, %1, %2" : "=v"(w1) : "v"(z_[n][2]), "v"(z_[n][3]));
      uint2 pw; pw.x = w0; pw.y = w1;
      *(uint2*)(&lP[w][la][(n * 16 + hi * 4) ^ ((la & 7) << 3)]) = pw;
    }
    {
      const u16* pr = &lP[w][la][0];
      bf16x8 pa0 = *(const bf16x8*)(pr + rcc);
      bf16x8 pa1 = *(const bf16x8*)(pr + (rcc ^ 32));
      __builtin_amdgcn_s_setprio(1);
#pragma unroll
      for (int f = 0; f < 4; ++f) {
        const u16* vr = &lVt[cur][f * 16 + la][0];
        bf16x8 v0 = *(const bf16x8*)(vr + rcc);
        bf16x8 v1 = *(const bf16x8*)(vr + (rcc ^ 32));
        ao[f] = __builtin_amdgcn_mfma_f32_16x16x32_bf16(pa0, v0, ao[f], 0, 0, 0);
        ao[f] = __builtin_amdgcn_mfma_f32_16x16x32_bf16(pa1, v1, ao[f], 0, 0, 0);
      }
      __builtin_amdgcn_s_setprio(0);
    }
    if (kt + 1 < nt) {
      const int nxt = cur ^ 1;
      *(u16x8*)(&lK[nxt][sr][sw])       = kreg0;
      *(u16x8*)(&lK[nxt][sr + 32][sw])  = kreg1;
      *(u16x8*)(&lVt[nxt][sr][sw])      = vreg0;
      *(u16x8*)(&lVt[nxt][sr + 32][sw]) = vreg1;
    }
  }
  l_ += __shfl_xor(l_, 16, 64);
  l_ += __shfl_xor(l_, 32, 64);
  float linv[4];
#pragma unroll
  for (int j = 0; j < 4; ++j) linv[j] = 1.0f / __shfl(l_, 4 * hi + j, 64);
#pragma unroll
  for (int f = 0; f < 4; ++f)
#pragma unroll
    for (int j = 0; j < 4; ++j) {
      int row = qr0 + hi * 4 + j;
      Ob[((size_t)(b * 2048 + row)) * 1024 + h * 64 + f * 16 + la] = f2b(ao[f][j] * linv[j]);
    }
}

extern "C" void kernel_launch(void* const* d_in, const int* in_sizes, int n_in,
                              void* d_out, int out_size, void* d_ws, size_t ws_size,
                              hipStream_t stream) {
  const float* x  = (const float*)d_in[0];   // (2,2048,1024) f32
  const float* wa = (const float*)d_in[1];   // (1024,1536)  f32
  const float* wp = (const float*)d_in[2];   // (1024,1024)  f32
  float* out = (float*)d_out;                // (2,2048,1024) f32
  char* ws = (char*)d_ws;
  u16* xb    = (u16*)(ws + 0);          // 4096x1024 bf16
  u16* waT   = (u16*)(ws + 8388608);    // 1536x1024 bf16
  u16* wpT   = (u16*)(ws + 11534336);   // 1024x1024 bf16
  u16* Qb    = (u16*)(ws + 26214400);   // [2][16][2048][64] bf16
  u16* Kb    = (u16*)(ws + 34603008);   // [2][4][2048][64] bf16
  u16* Vtb   = (u16*)(ws + 36700160);   // [2][4][64][2048] bf16
  u16* Ob    = (u16*)(ws + 38797312);   // 4096x1024 bf16
  float2* rt = (float2*)(ws + 47185920); // 2048x32 float2 (512KB)

  k_prep<<<4864, 256, 0, stream>>>(x, wa, wp, xb, waT, wpT, rt);
  k_gemm1<<<dim3(12, 64), 256, 0, stream>>>(xb, waT, rt, Qb, Kb, Vtb);
  k_attn<<<dim3(32, 32), 256, 0, stream>>>(Qb, Kb, Vtb, Ob);
  k_gemm_bt<0><<<dim3(8, 64), 256, 0, stream>>>(Ob, wpT, out, 4096, 1024, 1024);
}